// Round 10
// baseline (384.225 us; speedup 1.0000x reference)
//
#include <hip/hip_runtime.h>

#define TSTEPS 2048
#define BATCH  4096
#define HID    4
#define CH     16              // timesteps per chunk (barrier period)
#define NCHUNK (TSTEPS/CH)     // 128 source chunks
#define NPH    (NCHUNK+2)      // 130 phases (fill/drain), even -> unroll by 2

__device__ __forceinline__ float fast_exp2(float x) {
#if __has_builtin(__builtin_amdgcn_exp2f)
  return __builtin_amdgcn_exp2f(x);
#else
  return exp2f(x);
#endif
}
__device__ __forceinline__ float fast_rcp(float x) {
#if __has_builtin(__builtin_amdgcn_rcpf)
  return __builtin_amdgcn_rcpf(x);
#else
  return 1.0f / x;
#endif
}

// Direct global->LDS 16B load: LDS dest = uniform base + lane*16, global src
// per-lane. No VGPR liveness -> the prefetch cannot be sunk by the compiler.
__device__ __forceinline__ void xload16(float* ldst, const float* gsrc) {
  __builtin_amdgcn_global_load_lds(
      (const __attribute__((address_space(1))) void*)gsrc,
      (__attribute__((address_space(3))) void*)ldst, 16, 0, 0);
}

// Replicated-state 3-wave layer-systolic RNN.
//   - lane owns ONE batch element; full r[4] state in registers; 4x4 matvec =
//     16 per-lane FMAs (tree depth 3); NO cross-lane ops in the recurrence.
//   - recurrence on r = 1/(1+exp2(a)), h = 1-2r folded into weights:
//       wave0:  a = c + (K*Wih) x      + (-2K*Whh) r
//       wave1/2:a = c + (-2K*Wih) rprev+ (-2K*Whh) r   (c absorbs Wih.1)
//   - wave l at phase p computes source chunk m = p - l (steps 16m..16m+15).
//   - h handoff: r[4] as float4 through double-buffered LDS (contiguous b128,
//     conflict-free). ONE raw s_barrier per phase; lgkmcnt(0) drained before
//     it; vmcnt NEVER drained in the loop (counted vmcnt(16) for x staging).
//   - x staged via global_load_lds into a 2-slot ring; refill for chunk m+2
//     issued AFTER chunk m fully consumed (same slot), 1 phase of coverage.
__global__ __launch_bounds__(192) void rnn_rep(
    const float* __restrict__ X,    // (T, B, H)
    const float* __restrict__ H0,   // (L, B, H)
    const float* __restrict__ Wih,  // (L, H, H)
    const float* __restrict__ Whh,  // (L, H, H)
    const float* __restrict__ bih,  // (L, H)
    const float* __restrict__ bhh,  // (L, H)
    float* __restrict__ Y)          // (T, B, H)
{
  const int lane = threadIdx.x & 63;
  const int wid  = threadIdx.x >> 6;            // 0,1,2 = layer index
  const int b    = blockIdx.x * 64 + lane;      // batch element owned
  const float K  = 2.8853900817779268f;         // 2*log2(e)

  __shared__ float xbuf[2][CH][64][HID];        // 32 KB x staging ring
  __shared__ float iface[2][2][CH][64][HID];    // 64 KB [l->l+1][par][u][lane]

  // Full 4x4 weights for this wave's layer, pre-transformed (see header).
  float wx[HID][HID], wh[HID][HID], cc[HID];
#pragma unroll
  for (int j = 0; j < HID; ++j) {
    float sih = 0.f, shh = 0.f;
#pragma unroll
    for (int k = 0; k < HID; ++k) {
      float a_ih = Wih[(wid*HID + j)*HID + k];
      float a_hh = Whh[(wid*HID + j)*HID + k];
      wx[j][k] = (wid == 0) ? K * a_ih : -2.f * K * a_ih;
      wh[j][k] = -2.f * K * a_hh;
      sih += a_ih; shh += a_hh;
    }
    cc[j] = K * (bih[wid*HID + j] + bhh[wid*HID + j] + shh
                 + ((wid == 0) ? 0.f : sih));
  }

  float r0, r1, r2, r3;                         // h = 1 - 2r
  {
    const float* h0p = H0 + (size_t)wid * BATCH * HID + (size_t)b * HID;
    r0 = 0.5f * (1.0f - h0p[0]);
    r1 = 0.5f * (1.0f - h0p[1]);
    r2 = 0.5f * (1.0f - h0p[2]);
    r3 = 0.5f * (1.0f - h0p[3]);
  }

  // Prime x pipeline (wave0): chunks 0,1 -> slots 0,1 (32 outstanding).
  if (wid == 0) {
#pragma unroll
    for (int u = 0; u < CH; ++u)
      xload16(&xbuf[0][u][0][0], X + ((size_t)(0*CH + u) * BATCH + b) * HID);
#pragma unroll
    for (int u = 0; u < CH; ++u)
      xload16(&xbuf[1][u][0][0], X + ((size_t)(1*CH + u) * BATCH + b) * HID);
  }

  auto phase = [&](int cph, int slot) {
    if (cph >= wid && cph <= NCHUNK - 1 + wid) {   // wave-uniform window
      const int m    = cph - wid;                  // source chunk
      const int base = m * CH;
      const int par  = m & 1;

      const float* vsrc;
      if (wid == 0) {
        // oldest 16 loads (this chunk) have landed in xbuf[slot]
        asm volatile("s_waitcnt vmcnt(16)" ::: "memory");
        __builtin_amdgcn_sched_barrier(0);
        vsrc = &xbuf[slot][0][0][0];
      } else {
        vsrc = &iface[wid-1][par][0][0][0];
      }

#pragma unroll
      for (int u = 0; u < CH; ++u) {
        float4 v = *(const float4*)(vsrc + ((size_t)u*64 + lane) * HID);

        // pre: c + Wx.v  (independent of recurrence, ILP-rich)
        float p0 = cc[0], p1 = cc[1], p2 = cc[2], p3 = cc[3];
        p0 = fmaf(wx[0][0], v.x, p0); p0 = fmaf(wx[0][1], v.y, p0);
        p0 = fmaf(wx[0][2], v.z, p0); p0 = fmaf(wx[0][3], v.w, p0);
        p1 = fmaf(wx[1][0], v.x, p1); p1 = fmaf(wx[1][1], v.y, p1);
        p1 = fmaf(wx[1][2], v.z, p1); p1 = fmaf(wx[1][3], v.w, p1);
        p2 = fmaf(wx[2][0], v.x, p2); p2 = fmaf(wx[2][1], v.y, p2);
        p2 = fmaf(wx[2][2], v.z, p2); p2 = fmaf(wx[2][3], v.w, p2);
        p3 = fmaf(wx[3][0], v.x, p3); p3 = fmaf(wx[3][1], v.y, p3);
        p3 = fmaf(wx[3][2], v.z, p3); p3 = fmaf(wx[3][3], v.w, p3);

        // recurrence part: a_j = p_j + Wh_j . r  (tree depth 3)
        float t0, t1;
        t0 = fmaf(wh[0][0], r0, p0); t1 = wh[0][1] * r1;
        t0 = fmaf(wh[0][2], r2, t0); t1 = fmaf(wh[0][3], r3, t1);
        float a0 = t0 + t1;
        t0 = fmaf(wh[1][0], r0, p1); t1 = wh[1][1] * r1;
        t0 = fmaf(wh[1][2], r2, t0); t1 = fmaf(wh[1][3], r3, t1);
        float a1 = t0 + t1;
        t0 = fmaf(wh[2][0], r0, p2); t1 = wh[2][1] * r1;
        t0 = fmaf(wh[2][2], r2, t0); t1 = fmaf(wh[2][3], r3, t1);
        float a2 = t0 + t1;
        t0 = fmaf(wh[3][0], r0, p3); t1 = wh[3][1] * r1;
        t0 = fmaf(wh[3][2], r2, t0); t1 = fmaf(wh[3][3], r3, t1);
        float a3 = t0 + t1;

        r0 = fast_rcp(fast_exp2(a0) + 1.0f);
        r1 = fast_rcp(fast_exp2(a1) + 1.0f);
        r2 = fast_rcp(fast_exp2(a2) + 1.0f);
        r3 = fast_rcp(fast_exp2(a3) + 1.0f);

        if (wid <= 1) {
          float4 rv = {r0, r1, r2, r3};
          *(float4*)(&iface[wid][par][u][lane][0]) = rv;
        } else {
          float4 hv = {fmaf(-2.f, r0, 1.f), fmaf(-2.f, r1, 1.f),
                       fmaf(-2.f, r2, 1.f), fmaf(-2.f, r3, 1.f)};
          *(float4*)(Y + ((size_t)(base + u) * BATCH + b) * HID) = hv;
        }
      }

      // Refill chunk m+2 into this (now fully consumed) slot. lgkmcnt(0)
      // first: guarantees the chunk's ds_reads completed before overwrite.
      if (wid == 0) {
        __builtin_amdgcn_sched_barrier(0);
        asm volatile("s_waitcnt lgkmcnt(0)" ::: "memory");
        __builtin_amdgcn_sched_barrier(0);
#pragma unroll
        for (int u = 0; u < CH; ++u) {
          int tn = base + 2*CH + u;
          if (tn > TSTEPS - 1) tn = TSTEPS - 1;   // clamped tail: unused
          xload16(&xbuf[slot][u][0][0], X + ((size_t)tn * BATCH + b) * HID);
        }
      }
    }

    // phase boundary: drain LDS ops (NOT vmcnt), then raw barrier.
    __builtin_amdgcn_sched_barrier(0);
    asm volatile("s_waitcnt lgkmcnt(0)" ::: "memory");
    __builtin_amdgcn_s_barrier();
    __builtin_amdgcn_sched_barrier(0);
  };

  for (int p = 0; p < NPH; p += 2) {   // 130 = 2 * 65, static slot parity
    phase(p + 0, 0);
    phase(p + 1, 1);
  }
}

extern "C" void kernel_launch(void* const* d_in, const int* in_sizes, int n_in,
                              void* d_out, int out_size, void* d_ws, size_t ws_size,
                              hipStream_t stream) {
  const float* X   = (const float*)d_in[0];
  const float* H0  = (const float*)d_in[1];
  const float* Wih = (const float*)d_in[2];
  const float* Whh = (const float*)d_in[3];
  const float* bih = (const float*)d_in[4];
  const float* bhh = (const float*)d_in[5];
  float* Y = (float*)d_out;

  // 64 blocks x 192 threads: 3 layer-waves per block, one batch per lane.
  rnn_rep<<<dim3(BATCH / 64), dim3(192), 0, stream>>>(X, H0, Wih, Whh, bih, bhh, Y);
}

// Round 11
// 308.367 us; speedup vs baseline: 1.2460x; 1.2460x over previous
//
#include <hip/hip_runtime.h>

#define TSTEPS 2048
#define BATCH  4096
#define HID    4
#define CH     32              // timesteps per chunk (barrier period)
#define NCHUNK (TSTEPS/CH)     // 64 source chunks
#define NPH    (NCHUNK+2)      // 66 phases (fill/drain), even -> unroll by 2

// Broadcast component k (0..3) to all 4 lanes of each quad via DPP quad_perm.
#define QB(v,k) __int_as_float(__builtin_amdgcn_update_dpp( \
    0, __float_as_int(v), (k)*0x55, 0xF, 0xF, true))

__device__ __forceinline__ float fast_exp2(float x) {
#if __has_builtin(__builtin_amdgcn_exp2f)
  return __builtin_amdgcn_exp2f(x);
#else
  return exp2f(x);
#endif
}
__device__ __forceinline__ float fast_rcp(float x) {
#if __has_builtin(__builtin_amdgcn_rcpf)
  return __builtin_amdgcn_rcpf(x);
#else
  return 1.0f / x;
#endif
}

// Direct global->LDS 16B load: LDS dest = uniform base + lane*16, global src
// per-lane. No VGPR liveness -> prefetch cannot be sunk by the compiler.
__device__ __forceinline__ void xload16(float* ldst, const float* gsrc) {
  __builtin_amdgcn_global_load_lds(
      (const __attribute__((address_space(1))) void*)gsrc,
      (__attribute__((address_space(3))) void*)ldst, 16, 0, 0);
}

// Dual-group quad-DPP 3-wave layer-systolic RNN.
//  - wave l (=wid) owns layer l; phase c processes source chunk m = c - wid.
//  - each wave carries TWO independent 16-batch groups (A,B): two independent
//    recurrences whose instruction streams interleave -> group B's issue
//    fills group A's latency stalls (chain: DPP->fma-tree->exp2->add->rcp).
//  - recurrence on r (h = 1-2r folded): a = ai + whp.r_quad,
//    whp = -2K*Whh row j, cb = K*(bih+bhh+Whh.1), wi = K*Wih row j, K=2log2e.
//  - handoff: h through double-buffered LDS iface; ONE raw s_barrier/phase;
//    lgkmcnt(0) drained before it; vmcnt counted (16), never drained in loop.
//  - x staged via 16B global_load_lds tiles: one instr = 2 timesteps x 2
//    groups x 16 batch x 4 comps; 16 instrs/chunk; 2-slot ring, refill after
//    consume (coverage ~1 phase >> HBM latency).
__global__ __launch_bounds__(192) void rnn_dual(
    const float* __restrict__ X,    // (T, B, H)
    const float* __restrict__ H0,   // (L, B, H)
    const float* __restrict__ Wih,  // (L, H, H)
    const float* __restrict__ Whh,  // (L, H, H)
    const float* __restrict__ bih,  // (L, H)
    const float* __restrict__ bhh,  // (L, H)
    float* __restrict__ Y)          // (T, B, H)
{
  const int lane = threadIdx.x & 63;
  const int wid  = threadIdx.x >> 6;            // 0,1,2 = layer index
  const int b0   = blockIdx.x * 32;             // block's batch base (32 wide)
  const int bA   = b0 + (lane >> 2);            // group A batch element
  const int j    = lane & 3;                    // component owned
  const float K  = 2.8853900817779268f;         // 2*log2(e)

  // xbuf[slot][u][grp][b16][c]  (32 KB): matches xload16 lane pattern
  //   (one instr at dest &xbuf[s][u0][0][0][0]: lane L -> u0+(L>>5),
  //    g=(L>>4)&1, b=L&15, 4 comps). Read stride per u = 128 floats.
  __shared__ float xbuf[2][CH][2][16][HID];
  // iface[l][par][u][grp][lane]  (64 KB): same 128-float u-stride.
  __shared__ float iface[2][2][CH][2][64];

  // This wave's layer weights (row j), pre-transformed.
  float wi[HID], whp[HID], cb;
  {
    float wsum = 0.0f;
#pragma unroll
    for (int k = 0; k < HID; ++k) {
      float whh = Whh[(wid*HID + j)*HID + k];
      whp[k] = -2.0f * K * whh;
      wsum  += whh;
      wi[k]  = Wih[(wid*HID + j)*HID + k] * K;
    }
    cb = (bih[wid*HID + j] + bhh[wid*HID + j] + wsum) * K;
  }

  float rA = 0.5f * (1.0f - H0[((size_t)wid*BATCH + bA)      * HID + j]);
  float rB = 0.5f * (1.0f - H0[((size_t)wid*BATCH + bA + 16) * HID + j]);

  // Prime x pipeline (wave0): chunks 0,1 -> slots 0,1 (32 outstanding).
  if (wid == 0) {
#pragma unroll
    for (int i = 0; i < 16; ++i) {
      int t = 0*CH + 2*i + (lane >> 5);
      xload16(&xbuf[0][2*i][0][0][0],
              X + ((size_t)t*BATCH + b0 + ((lane >> 4) & 1)*16 + (lane & 15))*HID);
    }
#pragma unroll
    for (int i = 0; i < 16; ++i) {
      int t = 1*CH + 2*i + (lane >> 5);
      xload16(&xbuf[1][2*i][0][0][0],
              X + ((size_t)t*BATCH + b0 + ((lane >> 4) & 1)*16 + (lane & 15))*HID);
    }
  }

  auto phase = [&](int c, int slot) {
    if (c >= wid && c <= NCHUNK - 1 + wid) {      // wave-uniform window
      const int m    = c - wid;                   // source chunk
      const int base = m * CH;
      const int par  = m & 1;

      const float* vsrc;
      if (wid == 0) {
        // this chunk's 16 staging loads have landed (m+1's 16 in flight)
        asm volatile("s_waitcnt vmcnt(16)" ::: "memory");
        __builtin_amdgcn_sched_barrier(0);
        vsrc = &xbuf[slot][0][0][0][0];
      } else {
        vsrc = &iface[wid-1][par][0][0][0];
      }

      // 1) input accumulators for both groups (recurrence-independent).
      float aiA[CH], aiB[CH];
#pragma unroll
      for (int u = 0; u < CH; ++u) {
        float vA = vsrc[u*128 + lane];
        float vB = vsrc[u*128 + 64 + lane];
        float a = cb;
        a = fmaf(QB(vA, 0), wi[0], a);
        a = fmaf(QB(vA, 1), wi[1], a);
        a = fmaf(QB(vA, 2), wi[2], a);
        a = fmaf(QB(vA, 3), wi[3], a);
        aiA[u] = a;
        float b = cb;
        b = fmaf(QB(vB, 0), wi[0], b);
        b = fmaf(QB(vB, 1), wi[1], b);
        b = fmaf(QB(vB, 2), wi[2], b);
        b = fmaf(QB(vB, 3), wi[3], b);
        aiB[u] = b;
      }

      // 2) two independent serial recurrences, interleaved.
#pragma unroll
      for (int u = 0; u < CH; ++u) {
        float tA0 = fmaf(QB(rA, 0), whp[0], aiA[u]);
        float tB0 = fmaf(QB(rB, 0), whp[0], aiB[u]);
        float tA1 =      QB(rA, 1) * whp[1];
        float tB1 =      QB(rB, 1) * whp[1];
        tA0 = fmaf(QB(rA, 2), whp[2], tA0);
        tB0 = fmaf(QB(rB, 2), whp[2], tB0);
        tA1 = fmaf(QB(rA, 3), whp[3], tA1);
        tB1 = fmaf(QB(rB, 3), whp[3], tB1);
        float eA = fast_exp2(tA0 + tA1);
        float eB = fast_exp2(tB0 + tB1);
        rA = fast_rcp(eA + 1.0f);
        rB = fast_rcp(eB + 1.0f);
        float hA = fmaf(-2.0f, rA, 1.0f);          // off-chain
        float hB = fmaf(-2.0f, rB, 1.0f);
        if (wid <= 1) {
          iface[wid][par][u][0][lane] = hA;
          iface[wid][par][u][1][lane] = hB;
        } else {
          Y[((size_t)(base + u)*BATCH + bA)      * HID + j] = hA;
          Y[((size_t)(base + u)*BATCH + bA + 16) * HID + j] = hB;
        }
      }

      // 3) refill chunk m+2 into this (consumed) slot. lgkmcnt(0) first:
      //    the chunk's ds_reads must be complete before overwrite.
      if (wid == 0) {
        __builtin_amdgcn_sched_barrier(0);
        asm volatile("s_waitcnt lgkmcnt(0)" ::: "memory");
        __builtin_amdgcn_sched_barrier(0);
#pragma unroll
        for (int i = 0; i < 16; ++i) {
          int t = (m + 2)*CH + 2*i + (lane >> 5);
          if (t > TSTEPS - 1) t = TSTEPS - 1;     // clamped tail: unused
          xload16(&xbuf[slot][2*i][0][0][0],
                  X + ((size_t)t*BATCH + b0 + ((lane >> 4) & 1)*16 + (lane & 15))*HID);
        }
      }
    }

    // phase boundary: drain LDS ops (NOT vmcnt), then raw barrier.
    __builtin_amdgcn_sched_barrier(0);
    asm volatile("s_waitcnt lgkmcnt(0)" ::: "memory");
    __builtin_amdgcn_s_barrier();
    __builtin_amdgcn_sched_barrier(0);
  };

  for (int p = 0; p < NPH; p += 2) {   // 66 = 2 * 33, static slot parity
    phase(p + 0, 0);
    phase(p + 1, 1);
  }
}

extern "C" void kernel_launch(void* const* d_in, const int* in_sizes, int n_in,
                              void* d_out, int out_size, void* d_ws, size_t ws_size,
                              hipStream_t stream) {
  const float* X   = (const float*)d_in[0];
  const float* H0  = (const float*)d_in[1];
  const float* Wih = (const float*)d_in[2];
  const float* Whh = (const float*)d_in[3];
  const float* bih = (const float*)d_in[4];
  const float* bhh = (const float*)d_in[5];
  float* Y = (float*)d_out;

  // 128 blocks x 192 threads: 3 layer-waves per block, 32 batch per block
  // (two 16-batch groups per wave).
  rnn_dual<<<dim3(BATCH / 32), dim3(192), 0, stream>>>(X, H0, Wih, Whh, bih, bhh, Y);
}

// Round 13
// 252.822 us; speedup vs baseline: 1.5197x; 1.2197x over previous
//
#include <hip/hip_runtime.h>

#define TSTEPS 2048
#define BATCH  4096
#define HID    4
#define STRIDE (BATCH*HID)    // 16384 floats per timestep slab
#define CH     32             // timesteps per chunk (barrier period)
#define NCHUNK (TSTEPS/CH)    // 64 source chunks
#define NPH    (NCHUNK+2)     // 66 phases = 3 * 22 (static xbuf slot rotation)

// Broadcast component k (0..3) to all 4 lanes of each quad via DPP quad_perm.
#define QB(v,k) __int_as_float(__builtin_amdgcn_update_dpp( \
    0, __float_as_int(v), (k)*0x55, 0xF, 0xF, true))

// exp2(a) to ~7e-9 rel error with ZERO transcendental ops:
// n = rint(a), f = a-n in [-1/2,1/2]; 2^f = Taylor deg-7 (remainder
// (ln2/2)^8/8! ~ 5e-9), Estrin form; scale by 2^n via exponent bits.
__device__ __forceinline__ float exp2_poly(float a) {
  float n  = __builtin_rintf(a);
  n = fminf(fmaxf(n, -126.0f), 126.0f);      // safety clamp (never hit)
  float f  = a - n;
  float f2 = f * f;
  float f4 = f2 * f2;
  float q0 = fmaf(f, 0.69314718055994531f, 1.0f);
  float q1 = fmaf(f, 0.05550410866482158f, 0.24022650695910071f);
  float q2 = fmaf(f, 0.00133335581464284f, 0.00961812910762848f);
  float q3 = fmaf(f, 1.52527338040598e-5f,  1.54035303933816e-4f);
  float r01 = fmaf(f2, q1, q0);
  float r23 = fmaf(f2, q3, q2);
  float p  = fmaf(f4, r23, r01);
  int   ni = (int)n;
  float sc = __int_as_float((unsigned)(ni + 127) << 23);
  return p * sc;
}

// 1/d to fp32 accuracy with ZERO transcendental ops: magic seed (rel err
// <=3.4e-2) + 3 Newton steps (squares each time -> 2e-12, below fp32 ulp).
__device__ __forceinline__ float nrcp(float d) {
  float s = __int_as_float(0x7EF127EAu - __float_as_int(d));
  s = s * fmaf(-d, s, 2.0f);
  s = s * fmaf(-d, s, 2.0f);
  s = s * fmaf(-d, s, 2.0f);
  return s;
}

// Direct global->LDS 4B load: LDS dest = base + lane*4 (wave-uniform base),
// global src per-lane. No VGPR liveness -> compiler cannot sink the prefetch.
__device__ __forceinline__ void xload(float* ldst, const float* gsrc) {
  __builtin_amdgcn_global_load_lds(
      (const __attribute__((address_space(1))) void*)gsrc,
      (__attribute__((address_space(3))) void*)ldst, 4, 0, 0);
}

// 3-wave layer-systolic, CH=32 — structure IDENTICAL to the 202us r9 kernel;
// single variable changed: v_exp/v_rcp -> exp2_poly/nrcp (no trans ops,
// fp32-accurate). Recurrence on r = 1/(1+exp2(a)), h = 1-2r folded into
// weights: whp = -2K*Whh, cb = K*(bih+bhh+Whh.1), wi = K*Wih, K = 2*log2(e).
// Wave l (=wid) owns layer l; phase c processes source chunk m = c - wid.
// h handoff through double-buffered LDS iface; ONE raw s_barrier per phase;
// lgkmcnt(0) drained before it; vmcnt counted (32), never drained in loop.
__global__ __launch_bounds__(192) void rnn_pipe(
    const float* __restrict__ X,    // (T, B, H)
    const float* __restrict__ H0,   // (L, B, H)
    const float* __restrict__ Wih,  // (L, H, H)
    const float* __restrict__ Whh,  // (L, H, H)
    const float* __restrict__ bih,  // (L, H)
    const float* __restrict__ bhh,  // (L, H)
    float* __restrict__ Y)          // (T, B, H)
{
  const int lane = threadIdx.x & 63;
  const int wid  = threadIdx.x >> 6;           // 0,1,2 = layer index
  const int g    = blockIdx.x * 64 + lane;     // global (b,j) unit
  const int j    = g & 3;
  const float K  = 2.8853900817779268f;        // 2*log2(e)

  __shared__ float iface[2][2][CH][64];        // 32 KB: [l->l+1][par][u][lane]
  __shared__ float xbuf[3][CH][64];            // 24 KB: x staging ring (wave0)

  // This wave's layer weights. wi: K*Wih row j. whp: -2K*Whh row j.
  // cb: K*(bih+bhh+Whh.1) (absorbs the h=1-2r substitution).
  float wi[HID], whp[HID], cb;
  {
    float wsum = 0.0f;
#pragma unroll
    for (int k = 0; k < HID; ++k) {
      float whh = Whh[(wid*HID + j)*HID + k];
      whp[k] = -2.0f * K * whh;
      wsum  += whh;
      wi[k]  = Wih[(wid*HID + j)*HID + k] * K;
    }
    cb = (bih[wid*HID + j] + bhh[wid*HID + j] + wsum) * K;
  }

  float r = 0.5f * (1.0f - H0[wid*STRIDE + g]);   // h = 1 - 2r

  const float* __restrict__ xp = X + g;

  // Prime the x pipeline: chunks 0,1 -> slots 0,1 (64 outstanding loads).
  if (wid == 0) {
    __builtin_amdgcn_sched_barrier(0);
    asm volatile("s_waitcnt vmcnt(0)" ::: "memory");  // clean vmcnt baseline
#pragma unroll
    for (int u = 0; u < CH; ++u)
      xload(&xbuf[0][u][0], xp + (size_t)(0*CH + u) * STRIDE);
#pragma unroll
    for (int u = 0; u < CH; ++u)
      xload(&xbuf[1][u][0], xp + (size_t)(1*CH + u) * STRIDE);
  }

  auto phase = [&](int c, int slot) {
    if (c >= wid && c <= NCHUNK - 1 + wid) {      // wave-uniform window
      const int m    = c - wid;                   // source chunk
      const int base = m * CH;
      const int par  = m & 1;

      // 1) input accumulators ai[u] (recurrence-independent, ILP-rich)
      const float* vsrc;
      if (wid == 0) {
        // oldest 32 loads (this chunk) have landed in xbuf[slot]
        asm volatile("s_waitcnt vmcnt(32)" ::: "memory");
        __builtin_amdgcn_sched_barrier(0);
        vsrc = &xbuf[slot][0][0];
      } else {
        vsrc = &iface[wid-1][par][0][0];
      }

      float ai[CH];
#pragma unroll
      for (int u = 0; u < CH; ++u) {
        float v = vsrc[u*64 + lane];
        float a = cb;
        a = fmaf(QB(v, 0), wi[0], a);
        a = fmaf(QB(v, 1), wi[1], a);
        a = fmaf(QB(v, 2), wi[2], a);
        a = fmaf(QB(v, 3), wi[3], a);
        ai[u] = a;
      }

      // 2) refill: chunk m+2 -> slot (slot+2)%3 (clamped tail loads unused;
      //    always 32 issues keeps the vmcnt invariant exact)
      if (wid == 0) {
#pragma unroll
        for (int u = 0; u < CH; ++u) {
          int tn = base + 2*CH + u;
          if (tn > TSTEPS - 1) tn = TSTEPS - 1;
          xload(&xbuf[(slot+2)%3][u][0], xp + (size_t)tn * STRIDE);
        }
      }

      // 3) serial recurrence on r: DPP quad-dot -> exp2_poly -> nrcp
#pragma unroll
      for (int u = 0; u < CH; ++u) {
        float t0 = fmaf(QB(r, 0), whp[0], ai[u]);
        float t1 =      QB(r, 1) * whp[1];
        t0 = fmaf(QB(r, 2), whp[2], t0);
        t1 = fmaf(QB(r, 3), whp[3], t1);
        float e = exp2_poly(t0 + t1);
        r = nrcp(e + 1.0f);
        float h = fmaf(-2.0f, r, 1.0f);           // off-chain
        if (wid <= 1) {
          iface[wid][par][u][lane] = h;
        } else {
          Y[(size_t)(base + u) * STRIDE + g] = h;
        }
      }
    }

    // phase boundary: drain LDS ops only (NOT vmcnt), then raw barrier.
    __builtin_amdgcn_sched_barrier(0);
    asm volatile("s_waitcnt lgkmcnt(0)" ::: "memory");
    __builtin_amdgcn_s_barrier();
    __builtin_amdgcn_sched_barrier(0);
  };

  for (int cb2 = 0; cb2 < NPH; cb2 += 3) {   // 66 = 3 * 22, static slots
    phase(cb2 + 0, 0);
    phase(cb2 + 1, 1);
    phase(cb2 + 2, 2);
  }
}

extern "C" void kernel_launch(void* const* d_in, const int* in_sizes, int n_in,
                              void* d_out, int out_size, void* d_ws, size_t ws_size,
                              hipStream_t stream) {
  const float* X   = (const float*)d_in[0];
  const float* H0  = (const float*)d_in[1];
  const float* Wih = (const float*)d_in[2];
  const float* Whh = (const float*)d_in[3];
  const float* bih = (const float*)d_in[4];
  const float* bhh = (const float*)d_in[5];
  float* Y = (float*)d_out;

  // 256 blocks x 192 threads: one block per CU, 3 layer-waves on 3 SIMDs.
  rnn_pipe<<<dim3(STRIDE / 64), dim3(192), 0, stream>>>(X, H0, Wih, Whh, bih, bhh, Y);
}